// Round 10
// baseline (993.732 us; speedup 1.0000x reference)
//
#include <hip/hip_runtime.h>

#define N_NODES 50000
#define N_EDGES 800000
#define E_TOT (N_EDGES + N_NODES)
#define D 128
#define N_GRAPHS 64
#define NEG_SLOPE 0.2f
#define MAXDEG 256
#define SCAN_BLK 1024
#define SCAN_GRID ((N_NODES + SCAN_BLK - 1) / SCAN_BLK)   // 49
#define NTILE 64
#define NBLK ((N_NODES + NTILE - 1) / NTILE)              // 782
#define SLICE_ELEMS ((size_t)N_NODES * 16)

typedef _Float16 f16x8 __attribute__((ext_vector_type(8)));
typedef float f32x4 __attribute__((ext_vector_type(4)));

__device__ __forceinline__ float wave_max(float v) {
  #pragma unroll
  for (int off = 32; off > 0; off >>= 1) v = fmaxf(v, __shfl_xor(v, off));
  return v;
}
__device__ __forceinline__ float wave_sum(float v) {
  #pragma unroll
  for (int off = 32; off > 0; off >>= 1) v += __shfl_xor(v, off);
  return v;
}

// ---------------- CSR build ----------------
__global__ void k_count(const int* __restrict__ ei, int* __restrict__ cnt) {
  int e = blockIdx.x * blockDim.x + threadIdx.x;
  if (e >= E_TOT) return;
  int dst = (e < N_EDGES) ? ei[N_EDGES + e] : (e - N_EDGES);
  atomicAdd(&cnt[dst], 1);
}

__global__ __launch_bounds__(SCAN_BLK) void k_scan1(const int* __restrict__ cnt,
                                                    int* __restrict__ rowptr,
                                                    int* __restrict__ partial) {
  __shared__ int sm[SCAN_BLK];
  int i = blockIdx.x * SCAN_BLK + threadIdx.x;
  int v = (i < N_NODES) ? cnt[i] : 0;
  sm[threadIdx.x] = v;
  __syncthreads();
  #pragma unroll
  for (int off = 1; off < SCAN_BLK; off <<= 1) {
    int t = (threadIdx.x >= off) ? sm[threadIdx.x - off] : 0;
    __syncthreads();
    sm[threadIdx.x] += t;
    __syncthreads();
  }
  if (i < N_NODES) rowptr[i + 1] = sm[threadIdx.x];
  if (threadIdx.x == SCAN_BLK - 1) partial[blockIdx.x] = sm[threadIdx.x];
}

__global__ void k_scan2(int* __restrict__ partial) {
  int lane = threadIdx.x;
  int v = (lane < SCAN_GRID) ? partial[lane] : 0;
  #pragma unroll
  for (int off = 1; off < 64; off <<= 1) {
    int t = __shfl_up(v, off);
    if (lane >= off) v += t;
  }
  if (lane < SCAN_GRID) partial[lane] = v;
}

__global__ __launch_bounds__(SCAN_BLK) void k_scan3(int* __restrict__ rowptr,
                                                    const int* __restrict__ partial) {
  int i = blockIdx.x * SCAN_BLK + threadIdx.x;
  if (i == 0) rowptr[0] = 0;
  if (i < N_NODES && blockIdx.x > 0) rowptr[i + 1] += partial[blockIdx.x - 1];
}

__global__ void k_fill(const int* __restrict__ ei, const int* __restrict__ rowptr,
                       int* __restrict__ fill, int* __restrict__ col) {
  int e = blockIdx.x * blockDim.x + threadIdx.x;
  if (e >= E_TOT) return;
  int src, dst;
  if (e < N_EDGES) { src = ei[e]; dst = ei[N_EDGES + e]; }
  else { src = e - N_EDGES; dst = src; }
  int pos = rowptr[dst] + atomicAdd(&fill[dst], 1);
  col[pos] = src;
}

// ---------------- degree-sort permutation ----------------
__global__ __launch_bounds__(256) void k_hist(const int* __restrict__ rowptr,
                                              int* __restrict__ hist) {
  int n = blockIdx.x * 256 + threadIdx.x;
  if (n >= N_NODES) return;
  int deg = rowptr[n + 1] - rowptr[n];
  atomicAdd(&hist[deg < 255 ? deg : 255], 1);
}

__global__ __launch_bounds__(256) void k_hscan(const int* __restrict__ hist,
                                               int* __restrict__ hoff) {
  __shared__ int sm[256];
  int t = threadIdx.x;
  sm[t] = hist[t];
  __syncthreads();
  #pragma unroll
  for (int off = 1; off < 256; off <<= 1) {
    int v = (t >= off) ? sm[t - off] : 0;
    __syncthreads();
    sm[t] += v;
    __syncthreads();
  }
  hoff[t] = sm[t] - hist[t];   // exclusive
}

__global__ __launch_bounds__(256) void k_perm(const int* __restrict__ rowptr,
                                              int* __restrict__ hoff,
                                              int* __restrict__ perm) {
  int n = blockIdx.x * 256 + threadIdx.x;
  if (n >= N_NODES) return;
  int deg = rowptr[n + 1] - rowptr[n];
  int rank = atomicAdd(&hoff[deg < 255 ? deg : 255], 1);
  perm[rank] = n;
}

// ---------------- all-layers W -> fp16 hi/lo fragment-order conversion ----------------
struct WPtrs {
  const float* w[4];
  _Float16* h[4];
  _Float16* l[4];
};
__global__ __launch_bounds__(256) void k_wconv_all(WPtrs p) {
  int layer = blockIdx.x >> 6;
  int e = (blockIdx.x & 63) * 256 + threadIdx.x;   // 0..16383
  int k = e >> 7, n = e & 127;
  float v = p.w[layer][e];
  _Float16 h = (_Float16)v;
  _Float16 lo = (_Float16)(v - (float)h);
  int idx = (n >> 4) * 2048 + (k >> 3) * 128 + (n & 15) * 8 + (k & 7);
  p.h[layer][idx] = h;
  p.l[layer][idx] = lo;
}

// ---------------- GEMM via fp16x2 split MFMA, slice-major H out + fused alpha dots ----------------
__global__ __launch_bounds__(256) void k_gemm_mfma(const float* __restrict__ X,
                                                   const _Float16* __restrict__ Whf,
                                                   const _Float16* __restrict__ Wlf,
                                                   float* __restrict__ Hs,
                                                   const float* __restrict__ asrc,
                                                   const float* __restrict__ adst,
                                                   float* __restrict__ alpha_s,
                                                   float* __restrict__ alpha_d) {
  __shared__ __align__(16) _Float16 AhL[8192];   // [w][kgf][r16][8]
  __shared__ __align__(16) _Float16 AlL[8192];
  const int tid = threadIdx.x;
  const int l = tid & 63;
  const int w = tid >> 6;
  const int rowbase = blockIdx.x * 64;

  #pragma unroll
  for (int p = 0; p < 4; ++p) {
    int row = p * 16 + (tid >> 4);
    int k0 = (tid & 15) * 8;
    int grow = rowbase + row;
    float xv[8];
    if (grow < N_NODES) {
      float4 f0 = *reinterpret_cast<const float4*>(&X[(size_t)grow * D + k0]);
      float4 f1 = *reinterpret_cast<const float4*>(&X[(size_t)grow * D + k0 + 4]);
      xv[0] = f0.x; xv[1] = f0.y; xv[2] = f0.z; xv[3] = f0.w;
      xv[4] = f1.x; xv[5] = f1.y; xv[6] = f1.z; xv[7] = f1.w;
    } else {
      #pragma unroll
      for (int j = 0; j < 8; ++j) xv[j] = 0.f;
    }
    f16x8 ah, al;
    #pragma unroll
    for (int j = 0; j < 8; ++j) {
      ah[j] = (_Float16)xv[j];
      al[j] = (_Float16)(xv[j] - (float)ah[j]);
    }
    int idx = (((row >> 4) * 16 + (k0 >> 3)) * 16 + (row & 15)) * 8;
    *reinterpret_cast<f16x8*>(&AhL[idx]) = ah;
    *reinterpret_cast<f16x8*>(&AlL[idx]) = al;
  }
  __syncthreads();

  f32x4 acc[8];
  #pragma unroll
  for (int cc = 0; cc < 8; ++cc) acc[cc] = (f32x4){0.f, 0.f, 0.f, 0.f};

  #pragma unroll
  for (int kt = 0; kt < 4; ++kt) {
    int aidx = w * 2048 + kt * 512 + l * 8;
    f16x8 ah = *reinterpret_cast<const f16x8*>(&AhL[aidx]);
    f16x8 al = *reinterpret_cast<const f16x8*>(&AlL[aidx]);
    #pragma unroll
    for (int cc = 0; cc < 8; ++cc) {
      int bidx = cc * 2048 + kt * 512 + l * 8;
      f16x8 bh = *reinterpret_cast<const f16x8*>(&Whf[bidx]);
      f16x8 bl = *reinterpret_cast<const f16x8*>(&Wlf[bidx]);
      acc[cc] = __builtin_amdgcn_mfma_f32_16x16x32_f16(ah, bh, acc[cc], 0, 0, 0);
      acc[cc] = __builtin_amdgcn_mfma_f32_16x16x32_f16(ah, bl, acc[cc], 0, 0, 0);
      acc[cc] = __builtin_amdgcn_mfma_f32_16x16x32_f16(al, bh, acc[cc], 0, 0, 0);
    }
  }

  const int myn = l & 15;
  const int rg4 = l >> 4;
  float asv[8], adv[8];
  #pragma unroll
  for (int cc = 0; cc < 8; ++cc) {
    asv[cc] = asrc[cc * 16 + myn];
    adv[cc] = adst[cc * 16 + myn];
  }
  #pragma unroll
  for (int reg = 0; reg < 4; ++reg) {
    int grow = rowbase + w * 16 + rg4 * 4 + reg;
    float ps = 0.f, pd = 0.f;
    #pragma unroll
    for (int cc = 0; cc < 8; ++cc) {
      float v = acc[cc][reg];
      ps = fmaf(v, asv[cc], ps);
      pd = fmaf(v, adv[cc], pd);
      if (grow < N_NODES)
        Hs[(size_t)cc * SLICE_ELEMS + (size_t)grow * 16 + myn] = v;
    }
    #pragma unroll
    for (int off = 1; off < 16; off <<= 1) {
      ps += __shfl_xor(ps, off);
      pd += __shfl_xor(pd, off);
    }
    if (grow < N_NODES && myn == 0) {
      alpha_s[grow] = ps;
      alpha_d[grow] = pd;
    }
  }
}

// ---------------- per-node softmax stats (m, 1/sum): 16 lanes per node, 4 nodes/wave ----------------
__global__ __launch_bounds__(256) void k_stats(const int* __restrict__ rowptr,
                                               const int* __restrict__ col,
                                               const float* __restrict__ alpha_s,
                                               const float* __restrict__ alpha_d,
                                               const int* __restrict__ perm,
                                               float2* __restrict__ snode) {
  int lane = threadIdx.x & 63;
  int w = threadIdx.x >> 6;
  int sub = lane >> 4;         // node within wave 0..3
  int t = lane & 15;
  int rank = blockIdx.x * 16 + w * 4 + sub;
  if (rank >= N_NODES) return;
  int node = perm[rank];
  int start = rowptr[node], deg = rowptr[node + 1] - start;
  float ad = alpha_d[node];

  float m = -1e30f;
  for (int j = t; j < deg; j += 16) {
    float e = alpha_s[col[start + j]] + ad;
    e = e >= 0.f ? e : NEG_SLOPE * e;
    m = fmaxf(m, e);
  }
  #pragma unroll
  for (int off = 1; off < 16; off <<= 1) m = fmaxf(m, __shfl_xor(m, off));

  float ds = 0.f;
  for (int j = t; j < deg; j += 16) {
    float e = alpha_s[col[start + j]] + ad;
    e = e >= 0.f ? e : NEG_SLOPE * e;
    ds += expf(e - m);
  }
  #pragma unroll
  for (int off = 1; off < 16; off <<= 1) ds += __shfl_xor(ds, off);

  if (t == 0) snode[node] = make_float2(m, 1.f / (ds + 1e-16f));
}

// ---------------- slice-tiled SpMM v3: lane owns (node, f-quad), inline weights, sorted ----------------
__global__ __launch_bounds__(256) void k_spmm(const float* __restrict__ Hs,
                                              const int* __restrict__ rowptr,
                                              const int* __restrict__ col,
                                              const float* __restrict__ alpha_s,
                                              const float* __restrict__ alpha_d,
                                              const float2* __restrict__ snode,
                                              const int* __restrict__ perm,
                                              const float* __restrict__ bias,
                                              float* __restrict__ O) {
  const int slice = blockIdx.x & 7;
  const int lane = threadIdx.x & 63;
  const int w = threadIdx.x >> 6;
  const int f4 = lane & 3;
  const int nsub = lane >> 2;        // 0..15
  int rank = (blockIdx.x >> 3) * 64 + w * 16 + nsub;
  if (rank >= N_NODES) return;
  int node = perm[rank];
  int start = rowptr[node], end = rowptr[node + 1];
  float ad = alpha_d[node];
  float2 mi = snode[node];
  const float* __restrict__ hsl = Hs + (size_t)slice * SLICE_ELEMS;

  f32x4 acc = {0.f, 0.f, 0.f, 0.f};
  for (int i = start; i < end; ++i) {
    int s = col[i];
    float e = alpha_s[s] + ad;
    e = e >= 0.f ? e : NEG_SLOPE * e;
    float wgt = expf(e - mi.x);
    f32x4 h = *reinterpret_cast<const f32x4*>(&hsl[(size_t)s * 16 + f4 * 4]);
    acc.x = fmaf(wgt, h.x, acc.x);
    acc.y = fmaf(wgt, h.y, acc.y);
    acc.z = fmaf(wgt, h.z, acc.z);
    acc.w = fmaf(wgt, h.w, acc.w);
  }
  f32x4 bv = *reinterpret_cast<const f32x4*>(&bias[slice * 16 + f4 * 4]);
  f32x4 o;
  o.x = fmaxf(fmaf(acc.x, mi.y, bv.x), 0.f);
  o.y = fmaxf(fmaf(acc.y, mi.y, bv.y), 0.f);
  o.z = fmaxf(fmaf(acc.z, mi.y, bv.z), 0.f);
  o.w = fmaxf(fmaf(acc.w, mi.y, bv.w), 0.f);
  *reinterpret_cast<f32x4*>(&O[(size_t)node * D + slice * 16 + f4 * 4]) = o;
}

// ---------------- post: y[node] = relu'd O row . fcW ----------------
__global__ __launch_bounds__(256) void k_post(const float* __restrict__ O,
                                              const float* __restrict__ fcW,
                                              float* __restrict__ ynode) {
  int wid = threadIdx.x >> 6;
  int lane = threadIdx.x & 63;
  int node = blockIdx.x * 4 + wid;
  if (node >= N_NODES) return;
  float2 o = *reinterpret_cast<const float2*>(&O[(size_t)node * D + lane * 2]);
  float2 wv = *reinterpret_cast<const float2*>(&fcW[lane * 2]);
  float y = o.x * wv.x + o.y * wv.y;
  y = wave_sum(y);
  if (lane == 0) ynode[node] = y;
}

// ---------------- finalize: per-graph mean of ynode + bias ----------------
__global__ __launch_bounds__(256) void k_final(const float* __restrict__ ynode,
                                               const int* __restrict__ batch,
                                               const float* __restrict__ fcb,
                                               float* __restrict__ out) {
  __shared__ float sm[256];
  int b = blockIdx.x;
  int tid = threadIdx.x;
  int lo = 0, hi = N_NODES;
  while (lo < hi) { int mid = (lo + hi) >> 1; if (batch[mid] < b) lo = mid + 1; else hi = mid; }
  int s0 = lo;
  lo = 0; hi = N_NODES;
  while (lo < hi) { int mid = (lo + hi) >> 1; if (batch[mid] < b + 1) lo = mid + 1; else hi = mid; }
  int s1 = lo;
  float sum = 0.f;
  for (int n = s0 + tid; n < s1; n += 256) sum += ynode[n];
  sm[tid] = sum;
  __syncthreads();
  #pragma unroll
  for (int off = 128; off > 0; off >>= 1) {
    if (tid < off) sm[tid] += sm[tid + off];
    __syncthreads();
  }
  if (tid == 0) out[b] = sm[0] / fmaxf((float)(s1 - s0), 1.f) + fcb[0];
}

extern "C" void kernel_launch(void* const* d_in, const int* in_sizes, int n_in,
                              void* d_out, int out_size, void* d_ws, size_t ws_size,
                              hipStream_t stream) {
  const float* x = (const float*)d_in[0];
  const int* ei = (const int*)d_in[1];
  const int* batch = (const int*)d_in[2];
  const float* W[4]   = {(const float*)d_in[3], (const float*)d_in[7],
                         (const float*)d_in[11], (const float*)d_in[15]};
  const float* asr[4] = {(const float*)d_in[4], (const float*)d_in[8],
                         (const float*)d_in[12], (const float*)d_in[16]};
  const float* adt[4] = {(const float*)d_in[5], (const float*)d_in[9],
                         (const float*)d_in[13], (const float*)d_in[17]};
  const float* bs[4]  = {(const float*)d_in[6], (const float*)d_in[10],
                         (const float*)d_in[14], (const float*)d_in[18]};
  const float* fcW = (const float*)d_in[19];
  const float* fcb = (const float*)d_in[20];
  float* out = (float*)d_out;

  char* ws = (char*)d_ws;
  size_t off = 0;
  float* Hs = (float*)(ws + off); off += (size_t)N_NODES * D * 4;   // slice-major H
  float* O  = (float*)(ws + off); off += (size_t)N_NODES * D * 4;   // row-major agg out
  float* alpha_s = (float*)(ws + off); off += (size_t)N_NODES * 4;
  float* alpha_d = (float*)(ws + off); off += (size_t)N_NODES * 4;
  int* cnt  = (int*)(ws + off); off += (size_t)N_NODES * 4;
  int* fill = (int*)(ws + off); off += (size_t)N_NODES * 4;         // contiguous after cnt
  int* rowptr = (int*)(ws + off); off += (size_t)(N_NODES + 1) * 4 + 12;
  int* col = (int*)(ws + off); off += (size_t)E_TOT * 4;
  float2* snode = (float2*)(ws + off); off += (size_t)N_NODES * 8;
  float* ynode = (float*)(ws + off); off += (size_t)N_NODES * 4;
  int* partial = (int*)(ws + off); off += ((size_t)SCAN_GRID * 4 + 15) & ~15ull;
  int* perm = (int*)(ws + off); off += (size_t)N_NODES * 4;
  int* hist = (int*)(ws + off); off += 256 * 4;
  int* hoff = (int*)(ws + off); off += 256 * 4;
  _Float16* Whf[4];
  _Float16* Wlf[4];
  for (int lyr = 0; lyr < 4; ++lyr) {
    Whf[lyr] = (_Float16*)(ws + off); off += (size_t)D * D * 2;
    Wlf[lyr] = (_Float16*)(ws + off); off += (size_t)D * D * 2;
  }
  (void)ws_size; (void)in_sizes; (void)n_in; (void)out_size;

  hipMemsetAsync(cnt, 0, (size_t)N_NODES * 4 * 2, stream);  // zero cnt + fill
  hipMemsetAsync(hist, 0, 256 * 4, stream);
  WPtrs wp;
  for (int lyr = 0; lyr < 4; ++lyr) { wp.w[lyr] = W[lyr]; wp.h[lyr] = Whf[lyr]; wp.l[lyr] = Wlf[lyr]; }
  k_wconv_all<<<256, 256, 0, stream>>>(wp);
  int eb = (E_TOT + 255) / 256;
  k_count<<<eb, 256, 0, stream>>>(ei, cnt);
  k_scan1<<<SCAN_GRID, SCAN_BLK, 0, stream>>>(cnt, rowptr, partial);
  k_scan2<<<1, 64, 0, stream>>>(partial);
  k_scan3<<<SCAN_GRID, SCAN_BLK, 0, stream>>>(rowptr, partial);
  k_fill<<<eb, 256, 0, stream>>>(ei, rowptr, fill, col);
  int nb = (N_NODES + 255) / 256;
  k_hist<<<nb, 256, 0, stream>>>(rowptr, hist);
  k_hscan<<<1, 256, 0, stream>>>(hist, hoff);
  k_perm<<<nb, 256, 0, stream>>>(rowptr, hoff, perm);

  const float* in = x;
  for (int l = 0; l < 4; ++l) {
    k_gemm_mfma<<<NBLK, 256, 0, stream>>>(in, Whf[l], Wlf[l], Hs, asr[l], adt[l],
                                          alpha_s, alpha_d);
    k_stats<<<(N_NODES + 15) / 16, 256, 0, stream>>>(rowptr, col, alpha_s, alpha_d,
                                                     perm, snode);
    k_spmm<<<NBLK * 8, 256, 0, stream>>>(Hs, rowptr, col, alpha_s, alpha_d, snode,
                                         perm, bs[l], O);
    in = O;
  }
  k_post<<<(N_NODES + 3) / 4, 256, 0, stream>>>(O, fcW, ynode);
  k_final<<<N_GRAPHS, 256, 0, stream>>>(ynode, batch, fcb, out);
}

// Round 11
// 411.221 us; speedup vs baseline: 2.4165x; 2.4165x over previous
//
#include <hip/hip_runtime.h>

#define N_NODES 50000
#define N_EDGES 800000
#define E_TOT (N_EDGES + N_NODES)
#define D 128
#define N_GRAPHS 64
#define NEG_SLOPE 0.2f
#define MAXDEG 256
#define SCAN_BLK 1024
#define SCAN_GRID ((N_NODES + SCAN_BLK - 1) / SCAN_BLK)   // 49

typedef _Float16 f16x8 __attribute__((ext_vector_type(8)));
typedef float f32x4 __attribute__((ext_vector_type(4)));

__device__ __forceinline__ float wave_max(float v) {
  #pragma unroll
  for (int off = 32; off > 0; off >>= 1) v = fmaxf(v, __shfl_xor(v, off));
  return v;
}
__device__ __forceinline__ float wave_sum(float v) {
  #pragma unroll
  for (int off = 32; off > 0; off >>= 1) v += __shfl_xor(v, off);
  return v;
}

// ---------------- CSR build ----------------
__global__ void k_count(const int* __restrict__ ei, int* __restrict__ cnt) {
  int e = blockIdx.x * blockDim.x + threadIdx.x;
  if (e >= E_TOT) return;
  int dst = (e < N_EDGES) ? ei[N_EDGES + e] : (e - N_EDGES);
  atomicAdd(&cnt[dst], 1);
}

__global__ __launch_bounds__(SCAN_BLK) void k_scan1(const int* __restrict__ cnt,
                                                    int* __restrict__ rowptr,
                                                    int* __restrict__ partial) {
  __shared__ int sm[SCAN_BLK];
  int i = blockIdx.x * SCAN_BLK + threadIdx.x;
  int v = (i < N_NODES) ? cnt[i] : 0;
  sm[threadIdx.x] = v;
  __syncthreads();
  #pragma unroll
  for (int off = 1; off < SCAN_BLK; off <<= 1) {
    int t = (threadIdx.x >= off) ? sm[threadIdx.x - off] : 0;
    __syncthreads();
    sm[threadIdx.x] += t;
    __syncthreads();
  }
  if (i < N_NODES) rowptr[i + 1] = sm[threadIdx.x];
  if (threadIdx.x == SCAN_BLK - 1) partial[blockIdx.x] = sm[threadIdx.x];
}

__global__ void k_scan2(int* __restrict__ partial) {
  int lane = threadIdx.x;
  int v = (lane < SCAN_GRID) ? partial[lane] : 0;
  #pragma unroll
  for (int off = 1; off < 64; off <<= 1) {
    int t = __shfl_up(v, off);
    if (lane >= off) v += t;
  }
  if (lane < SCAN_GRID) partial[lane] = v;
}

__global__ __launch_bounds__(SCAN_BLK) void k_scan3(int* __restrict__ rowptr,
                                                    const int* __restrict__ partial) {
  int i = blockIdx.x * SCAN_BLK + threadIdx.x;
  if (i == 0) rowptr[0] = 0;
  if (i < N_NODES && blockIdx.x > 0) rowptr[i + 1] += partial[blockIdx.x - 1];
}

__global__ void k_fill(const int* __restrict__ ei, const int* __restrict__ rowptr,
                       int* __restrict__ fill, int* __restrict__ col) {
  int e = blockIdx.x * blockDim.x + threadIdx.x;
  if (e >= E_TOT) return;
  int src, dst;
  if (e < N_EDGES) { src = ei[e]; dst = ei[N_EDGES + e]; }
  else { src = e - N_EDGES; dst = src; }
  int pos = rowptr[dst] + atomicAdd(&fill[dst], 1);
  col[pos] = src;
}

// ---------------- all-layers W -> fp16 hi/lo fragment-order conversion ----------------
struct WPtrs {
  const float* w[4];
  _Float16* h[4];
  _Float16* l[4];
};
__global__ __launch_bounds__(256) void k_wconv_all(WPtrs p) {
  int layer = blockIdx.x >> 6;
  int e = (blockIdx.x & 63) * 256 + threadIdx.x;   // 0..16383
  int k = e >> 7, n = e & 127;
  float v = p.w[layer][e];
  _Float16 h = (_Float16)v;
  _Float16 lo = (_Float16)(v - (float)h);
  int idx = (n >> 4) * 2048 + (k >> 3) * 128 + (n & 15) * 8 + (k & 7);
  p.h[layer][idx] = h;
  p.l[layer][idx] = lo;
}

// ---------------- GEMM via fp16x2 split MFMA + fused alpha dots ----------------
__global__ __launch_bounds__(256) void k_gemm_mfma(const float* __restrict__ X,
                                                   const _Float16* __restrict__ Whf,
                                                   const _Float16* __restrict__ Wlf,
                                                   float* __restrict__ H,
                                                   const float* __restrict__ asrc,
                                                   const float* __restrict__ adst,
                                                   float* __restrict__ alpha_s,
                                                   float* __restrict__ alpha_d) {
  __shared__ __align__(16) _Float16 AhL[8192];   // [w][kgf][r16][8]
  __shared__ __align__(16) _Float16 AlL[8192];
  const int tid = threadIdx.x;
  const int l = tid & 63;
  const int w = tid >> 6;
  const int rowbase = blockIdx.x * 64;

  #pragma unroll
  for (int p = 0; p < 4; ++p) {
    int row = p * 16 + (tid >> 4);
    int k0 = (tid & 15) * 8;
    int grow = rowbase + row;
    float xv[8];
    if (grow < N_NODES) {
      float4 f0 = *reinterpret_cast<const float4*>(&X[(size_t)grow * D + k0]);
      float4 f1 = *reinterpret_cast<const float4*>(&X[(size_t)grow * D + k0 + 4]);
      xv[0] = f0.x; xv[1] = f0.y; xv[2] = f0.z; xv[3] = f0.w;
      xv[4] = f1.x; xv[5] = f1.y; xv[6] = f1.z; xv[7] = f1.w;
    } else {
      #pragma unroll
      for (int j = 0; j < 8; ++j) xv[j] = 0.f;
    }
    f16x8 ah, al;
    #pragma unroll
    for (int j = 0; j < 8; ++j) {
      ah[j] = (_Float16)xv[j];
      al[j] = (_Float16)(xv[j] - (float)ah[j]);
    }
    int idx = (((row >> 4) * 16 + (k0 >> 3)) * 16 + (row & 15)) * 8;
    *reinterpret_cast<f16x8*>(&AhL[idx]) = ah;
    *reinterpret_cast<f16x8*>(&AlL[idx]) = al;
  }
  __syncthreads();

  f32x4 acc[8];
  #pragma unroll
  for (int cc = 0; cc < 8; ++cc) acc[cc] = (f32x4){0.f, 0.f, 0.f, 0.f};

  #pragma unroll
  for (int kt = 0; kt < 4; ++kt) {
    int aidx = w * 2048 + kt * 512 + l * 8;
    f16x8 ah = *reinterpret_cast<const f16x8*>(&AhL[aidx]);
    f16x8 al = *reinterpret_cast<const f16x8*>(&AlL[aidx]);
    #pragma unroll
    for (int cc = 0; cc < 8; ++cc) {
      int bidx = cc * 2048 + kt * 512 + l * 8;
      f16x8 bh = *reinterpret_cast<const f16x8*>(&Whf[bidx]);
      f16x8 bl = *reinterpret_cast<const f16x8*>(&Wlf[bidx]);
      acc[cc] = __builtin_amdgcn_mfma_f32_16x16x32_f16(ah, bh, acc[cc], 0, 0, 0);
      acc[cc] = __builtin_amdgcn_mfma_f32_16x16x32_f16(ah, bl, acc[cc], 0, 0, 0);
      acc[cc] = __builtin_amdgcn_mfma_f32_16x16x32_f16(al, bh, acc[cc], 0, 0, 0);
    }
  }

  const int myn = l & 15;
  const int rg4 = l >> 4;
  float asv[8], adv[8];
  #pragma unroll
  for (int cc = 0; cc < 8; ++cc) {
    asv[cc] = asrc[cc * 16 + myn];
    adv[cc] = adst[cc * 16 + myn];
  }
  #pragma unroll
  for (int reg = 0; reg < 4; ++reg) {
    int grow = rowbase + w * 16 + rg4 * 4 + reg;
    float ps = 0.f, pd = 0.f;
    #pragma unroll
    for (int cc = 0; cc < 8; ++cc) {
      float v = acc[cc][reg];
      ps = fmaf(v, asv[cc], ps);
      pd = fmaf(v, adv[cc], pd);
      if (grow < N_NODES) H[(size_t)grow * D + cc * 16 + myn] = v;
    }
    #pragma unroll
    for (int off = 1; off < 16; off <<= 1) {
      ps += __shfl_xor(ps, off);
      pd += __shfl_xor(pd, off);
    }
    if (grow < N_NODES && myn == 0) {
      alpha_s[grow] = ps;
      alpha_d[grow] = pd;
    }
  }
}

// ---------------- fused segment softmax + aggregate + bias + relu ----------------
template <int FINAL>
__global__ __launch_bounds__(256) void k_agg(const float* __restrict__ H,
                                             const int* __restrict__ rowptr,
                                             const int* __restrict__ col,
                                             const float* __restrict__ alpha_s,
                                             const float* __restrict__ alpha_d,
                                             const float* __restrict__ bias,
                                             float* __restrict__ Out,
                                             const float* __restrict__ fcW,
                                             float* __restrict__ ynode) {
  __shared__ float wls[4][MAXDEG];
  __shared__ int cls[4][MAXDEG];
  int wid = threadIdx.x >> 6;
  int lane = threadIdx.x & 63;
  int node = blockIdx.x * 4 + wid;
  if (node >= N_NODES) return;
  int start = rowptr[node], end = rowptr[node + 1];
  int deg = end - start;
  float ad = alpha_d[node];

  // pass 1: e into registers + cols into LDS, wave max
  float earr[4];
  float m = -1e30f;
  #pragma unroll
  for (int k = 0; k < 4; ++k) {
    int j0 = lane + k * 64;
    earr[k] = -1e30f;
    if (j0 < deg) {
      int s = col[start + j0];
      float e = alpha_s[s] + ad;
      e = e >= 0.f ? e : NEG_SLOPE * e;
      cls[wid][j0] = s;
      earr[k] = e;
    }
  }
  m = fmaxf(fmaxf(earr[0], earr[1]), fmaxf(earr[2], earr[3]));
  for (int j0 = MAXDEG + lane; j0 < deg; j0 += 64) {
    int s = col[start + j0];
    float e = alpha_s[s] + ad;
    e = e >= 0.f ? e : NEG_SLOPE * e;
    m = fmaxf(m, e);
  }
  m = wave_max(m);

  // pass 2: weights into LDS, wave sum
  float dsum = 0.f;
  #pragma unroll
  for (int k = 0; k < 4; ++k) {
    int j0 = lane + k * 64;
    if (j0 < deg) {
      float w = expf(earr[k] - m);
      wls[wid][j0] = w;
      dsum += w;
    }
  }
  for (int j0 = MAXDEG + lane; j0 < deg; j0 += 64) {
    int s = col[start + j0];
    float e = alpha_s[s] + ad;
    e = e >= 0.f ? e : NEG_SLOPE * e;
    dsum += expf(e - m);
  }
  dsum = wave_sum(dsum);
  float inv = 1.f / (dsum + 1e-16f);

  // pass 3: gather in masked batches of 8 (8 loads in flight, no serial tail)
  float2 acc = make_float2(0.f, 0.f);
  int degc = deg < MAXDEG ? deg : MAXDEG;
  for (int jj = 0; jj < degc; jj += 8) {
    float w[8];
    float2 hv[8];
    #pragma unroll
    for (int u = 0; u < 8; ++u) {
      int idx = jj + u;
      bool ok = idx < degc;
      int s = ok ? cls[wid][idx] : cls[wid][0];
      w[u] = ok ? wls[wid][idx] : 0.f;
      hv[u] = *reinterpret_cast<const float2*>(&H[(size_t)s * D + lane * 2]);
    }
    #pragma unroll
    for (int u = 0; u < 8; ++u) {
      acc.x = fmaf(w[u], hv[u].x, acc.x);
      acc.y = fmaf(w[u], hv[u].y, acc.y);
    }
  }
  for (int jj = MAXDEG; jj < deg; ++jj) {   // cold fallback
    int s = col[start + jj];
    float e = alpha_s[s] + ad;
    e = e >= 0.f ? e : NEG_SLOPE * e;
    float w = expf(e - m);
    float2 hv = *reinterpret_cast<const float2*>(&H[(size_t)s * D + lane * 2]);
    acc.x = fmaf(w, hv.x, acc.x);
    acc.y = fmaf(w, hv.y, acc.y);
  }

  float2 bv = *reinterpret_cast<const float2*>(&bias[lane * 2]);
  float ox = fmaxf(acc.x * inv + bv.x, 0.f);
  float oy = fmaxf(acc.y * inv + bv.y, 0.f);
  if (FINAL) {
    float2 wv = *reinterpret_cast<const float2*>(&fcW[lane * 2]);
    float y = wave_sum(ox * wv.x + oy * wv.y);
    if (lane == 0) ynode[node] = y;
  } else {
    *reinterpret_cast<float2*>(&Out[(size_t)node * D + lane * 2]) = make_float2(ox, oy);
  }
}

// ---------------- finalize: per-graph mean of ynode + bias ----------------
__global__ __launch_bounds__(256) void k_final(const float* __restrict__ ynode,
                                               const int* __restrict__ batch,
                                               const float* __restrict__ fcb,
                                               float* __restrict__ out) {
  __shared__ float sm[256];
  int b = blockIdx.x;
  int tid = threadIdx.x;
  int lo = 0, hi = N_NODES;
  while (lo < hi) { int mid = (lo + hi) >> 1; if (batch[mid] < b) lo = mid + 1; else hi = mid; }
  int s0 = lo;
  lo = 0; hi = N_NODES;
  while (lo < hi) { int mid = (lo + hi) >> 1; if (batch[mid] < b + 1) lo = mid + 1; else hi = mid; }
  int s1 = lo;
  float sum = 0.f;
  for (int n = s0 + tid; n < s1; n += 256) sum += ynode[n];
  sm[tid] = sum;
  __syncthreads();
  #pragma unroll
  for (int off = 128; off > 0; off >>= 1) {
    if (tid < off) sm[tid] += sm[tid + off];
    __syncthreads();
  }
  if (tid == 0) out[b] = sm[0] / fmaxf((float)(s1 - s0), 1.f) + fcb[0];
}

extern "C" void kernel_launch(void* const* d_in, const int* in_sizes, int n_in,
                              void* d_out, int out_size, void* d_ws, size_t ws_size,
                              hipStream_t stream) {
  const float* x = (const float*)d_in[0];
  const int* ei = (const int*)d_in[1];
  const int* batch = (const int*)d_in[2];
  const float* W[4]   = {(const float*)d_in[3], (const float*)d_in[7],
                         (const float*)d_in[11], (const float*)d_in[15]};
  const float* asr[4] = {(const float*)d_in[4], (const float*)d_in[8],
                         (const float*)d_in[12], (const float*)d_in[16]};
  const float* adt[4] = {(const float*)d_in[5], (const float*)d_in[9],
                         (const float*)d_in[13], (const float*)d_in[17]};
  const float* bs[4]  = {(const float*)d_in[6], (const float*)d_in[10],
                         (const float*)d_in[14], (const float*)d_in[18]};
  const float* fcW = (const float*)d_in[19];
  const float* fcb = (const float*)d_in[20];
  float* out = (float*)d_out;

  char* ws = (char*)d_ws;
  size_t off = 0;
  float* hA = (float*)(ws + off); off += (size_t)N_NODES * D * 4;
  float* hB = (float*)(ws + off); off += (size_t)N_NODES * D * 4;
  float* alpha_s = (float*)(ws + off); off += (size_t)N_NODES * 4;
  float* alpha_d = (float*)(ws + off); off += (size_t)N_NODES * 4;
  int* cnt  = (int*)(ws + off); off += (size_t)N_NODES * 4;
  int* fill = (int*)(ws + off); off += (size_t)N_NODES * 4;
  int* rowptr = (int*)(ws + off); off += (size_t)(N_NODES + 1) * 4 + 12;
  int* col = (int*)(ws + off); off += (size_t)E_TOT * 4;
  float* ynode = (float*)(ws + off); off += (size_t)N_NODES * 4;
  int* partial = (int*)(ws + off); off += ((size_t)SCAN_GRID * 4 + 15) & ~15ull;
  _Float16* Whf[4];
  _Float16* Wlf[4];
  for (int lyr = 0; lyr < 4; ++lyr) {
    Whf[lyr] = (_Float16*)(ws + off); off += (size_t)D * D * 2;
    Wlf[lyr] = (_Float16*)(ws + off); off += (size_t)D * D * 2;
  }
  (void)ws_size; (void)in_sizes; (void)n_in; (void)out_size;

  hipMemsetAsync(cnt, 0, (size_t)N_NODES * 4 * 2, stream);  // zero cnt + fill
  WPtrs wp;
  for (int lyr = 0; lyr < 4; ++lyr) { wp.w[lyr] = W[lyr]; wp.h[lyr] = Whf[lyr]; wp.l[lyr] = Wlf[lyr]; }
  k_wconv_all<<<256, 256, 0, stream>>>(wp);
  int eb = (E_TOT + 255) / 256;
  k_count<<<eb, 256, 0, stream>>>(ei, cnt);
  k_scan1<<<SCAN_GRID, SCAN_BLK, 0, stream>>>(cnt, rowptr, partial);
  k_scan2<<<1, 64, 0, stream>>>(partial);
  k_scan3<<<SCAN_GRID, SCAN_BLK, 0, stream>>>(rowptr, partial);
  k_fill<<<eb, 256, 0, stream>>>(ei, rowptr, fill, col);

  const float* in = x;
  for (int l = 0; l < 4; ++l) {
    k_gemm_mfma<<<(N_NODES + 63) / 64, 256, 0, stream>>>(in, Whf[l], Wlf[l], hA,
                                                         asr[l], adt[l], alpha_s, alpha_d);
    if (l < 3) {
      k_agg<0><<<(N_NODES + 3) / 4, 256, 0, stream>>>(hA, rowptr, col, alpha_s, alpha_d,
                                                      bs[l], hB, nullptr, nullptr);
    } else {
      k_agg<1><<<(N_NODES + 3) / 4, 256, 0, stream>>>(hA, rowptr, col, alpha_s, alpha_d,
                                                      bs[l], nullptr, fcW, ynode);
    }
    in = hB;
  }
  k_final<<<N_GRAPHS, 256, 0, stream>>>(ynode, batch, fcb, out);
}